// Round 8
// baseline (71.327 us; speedup 1.0000x reference)
//
#include <hip/hip_runtime.h>

// OTAM cumulative-distance matching, fused forward+transposed DP, one pass.
// similarity: [2048, 128, 16, 16] f32 ; out: [2048, 128] f32
//
// v8 = v7 + DRAM page pairing: two 2-row chunks staged per superstep from
// two register groups (A,B); the NEXT superstep's two load groups are issued
// back-to-back, so same-pair adjacent 128B lines (same DRAM page) arrive at
// the memory controller together. 2-wave blocks, 16 KB LDS per wave
// (2 chunk slots), wave-private (no barriers), compiler-tracked waits only.

#define K2   14.4269504088896340736f   // 1/(lambda*ln2), lambda = 0.1
#define LL2  0.069314718055994530942f  // lambda*ln(2)

// softmin(a,b) = min - L*ln2*log2(1 + exp2(-|a-b|/(L*ln2)))
__device__ __forceinline__ float softmin2(float a, float b) {
    float mn = fminf(a, b);
    float t  = __builtin_amdgcn_exp2f(-K2 * fabsf(a - b));
    return mn - LL2 * __builtin_amdgcn_logf(1.0f + t);   // logf = v_log_f32 = log2
}

__device__ __forceinline__ float softmin3(float a, float b, float c) {
    float mn = fminf(fminf(a, b), c);   // v_min3_f32
    float s = __builtin_amdgcn_exp2f(-K2 * (a - mn))
            + __builtin_amdgcn_exp2f(-K2 * (b - mn))
            + __builtin_amdgcn_exp2f(-K2 * (c - mn));
    return mn - LL2 * __builtin_amdgcn_logf(s);
}

// DP1 (row-major over D): one row step, in-place with diagonal carry.
__device__ __forceinline__ void dp_row(float* R, const float* dr) {
    float diag = R[0];              // cum1[r-1, 0] = 0
    float oldR = R[1];
    R[1] = dr[0] + softmin3(diag, R[0], oldR);   // m = 1 boundary
    diag = oldR;
#pragma unroll
    for (int m = 2; m <= 16; ++m) {
        float o = R[m];
        R[m] = dr[m - 1] + softmin2(diag, R[m - 1]);
        diag = o;
    }
    R[17] = softmin3(diag, R[16], R[17]);        // m = 17 pad, d = 0, boundary
}

// DP2 (the DP on D^T, advanced column-major): one interior column step.
__device__ __forceinline__ void dp_col(float* C, const float* dr) {
    float diag2 = C[0];             // cum2[0, m-1]
    C[0] = C[0] + dr[0];            // row 0 of DP2 is a plain cumsum
#pragma unroll
    for (int l = 1; l < 16; ++l) {
        float o = C[l];
        C[l] = dr[l] + softmin2(diag2, o);
        diag2 = o;
    }
}

__global__ __launch_bounds__(128, 3)
void otam_fused_kernel(const float* __restrict__ sim, float* __restrict__ out) {
    const int t  = threadIdx.x & 63;
    const int wv = threadIdx.x >> 6;                 // 0..1
    const int pair0 = blockIdx.x * 128 + wv * 64;

    __shared__ float lds_all[2 * 4096];              // 32 KB: 2 waves x 16 KB
    float* lds = lds_all + (wv << 12);               // wave-private -> no barriers

    const int u = t >> 3;                            // 0..7
    const int c = t & 7;                             // 0..7

    // chunk cc (2 rows): instr i -> pair (pair0 + i*8 + u), bytes cc*128 + c*16
    const float* gbase = sim + (((size_t)(pair0 + u)) << 8) + (c << 2);
    // LDS write base (floats): slot-local addr (u*8 + (c^u))*4 ; + i*256 / instr
    float* wbase = lds + ((u * 8 + (c ^ u)) << 2);

    float R[18], C[16], dr[16];
    float4 A[8], B[8];

#define LOADG(buf, cc)                                                             \
    _Pragma("unroll")                                                              \
    for (int i = 0; i < 8; ++i)                                                    \
        buf[i] = *reinterpret_cast<const float4*>(gbase + i * 2048 + (cc) * 32);

#define WRITEG(buf, slot)                                                          \
    _Pragma("unroll")                                                              \
    for (int i = 0; i < 8; ++i) {                                                  \
        float4 w;                                                                  \
        w.x = 1.0f - buf[i].x; w.y = 1.0f - buf[i].y;                              \
        w.z = 1.0f - buf[i].z; w.w = 1.0f - buf[i].w;                              \
        *reinterpret_cast<float4*>(wbase + (slot) * 2048 + i * 256) = w;           \
    }

    // rr = 0..3 within superstep: slot rr>>1, sub-row rr&1
#define READR(rr)                                                                  \
    _Pragma("unroll")                                                              \
    for (int k = 0; k < 4; ++k) {                                                  \
        float4 v = *reinterpret_cast<const float4*>(                               \
            lds + ((rr) >> 1) * 2048 + t * 32 + (((((rr) & 1) * 4 + k) ^ c) << 2)); \
        dr[k * 4 + 0] = v.x; dr[k * 4 + 1] = v.y;                                  \
        dr[k * 4 + 2] = v.z; dr[k * 4 + 3] = v.w;                                  \
    }

    // ---------- superstep 0 (chunks 0,1 = rows 0..3) ----------
    LOADG(A, 0);
    LOADG(B, 1);
    WRITEG(A, 0);        // waits A (B outstanding)
    LOADG(A, 2);         // next superstep, page-adjacent to B's lines
    WRITEG(B, 1);        // waits B (next-A outstanding)
    LOADG(B, 3);

    // row 0: DP1 row 0 = cumsum; DP2 column m=1 (boundary)
    READR(0);
    R[0] = 0.0f;
#pragma unroll
    for (int m = 1; m <= 16; ++m) R[m] = R[m - 1] + dr[m - 1];
    R[17] = R[16];
    C[0] = dr[0];
#pragma unroll
    for (int l = 1; l < 16; ++l)
        C[l] = dr[l] + softmin3(0.0f, 0.0f, C[l - 1]);

    READR(1); dp_row(R, dr); dp_col(C, dr);
    READR(2); dp_row(R, dr); dp_col(C, dr);
    READR(3); dp_row(R, dr); dp_col(C, dr);

    // ---------- supersteps 1..3 (rows 4..15) ----------
    for (int s = 1; s < 4; ++s) {
        WRITEG(A, 0);                    // waits A-chunk (B outstanding)
        if (s < 3) LOADG(A, 2 * s + 2);
        WRITEG(B, 1);
        if (s < 3) LOADG(B, 2 * s + 3);
        READR(0); dp_row(R, dr); dp_col(C, dr);
        READR(1); dp_row(R, dr); dp_col(C, dr);
        READR(2); dp_row(R, dr); dp_col(C, dr);
        READR(3); dp_row(R, dr); dp_col(C, dr);
    }

    // ---------- DP2 final column m = 17 (d = 0, boundary) ----------
    {
        float diag2 = C[0];
#pragma unroll
        for (int l = 1; l < 16; ++l) {
            float o = C[l];
            C[l] = softmin3(diag2, o, C[l - 1]);
            diag2 = o;
        }
    }

    out[pair0 + t] = -0.5f * (R[17] + C[15]);
#undef LOADG
#undef WRITEG
#undef READR
}

extern "C" void kernel_launch(void* const* d_in, const int* in_sizes, int n_in,
                              void* d_out, int out_size, void* d_ws, size_t ws_size,
                              hipStream_t stream) {
    const float* sim = (const float*)d_in[0];
    float* out = (float*)d_out;
    int npairs = in_sizes[0] >> 8;          // 262144
    int grid = npairs >> 7;                 // 128 pairs per block
    otam_fused_kernel<<<grid, 128, 0, stream>>>(sim, out);
}

// Round 10
// 56.037 us; speedup vs baseline: 1.2729x; 1.2729x over previous
//
#include <hip/hip_runtime.h>

// OTAM cumulative-distance matching, fused forward+transposed DP, one pass.
// similarity: [2048, 128, 16, 16] f32 ; out: [2048, 128] f32
//
// v10 = v7 (proven 53.0us) + nontemporal global loads, via clang native
// vector type (ext_vector_type(4)) because __builtin_nontemporal_load does
// not accept HIP_vector_type struct pointers. The input stream has zero
// reuse (each 128B line fetched exactly once by exactly one instruction),
// so the nt/streaming hint removes L2 allocation overhead for the 268MB
// stream. No other change vs v7: same addresses, same schedule, all memory
// waits compiler-tracked.

typedef float f32x4 __attribute__((ext_vector_type(4)));

#define K2   14.4269504088896340736f   // 1/(lambda*ln2), lambda = 0.1
#define LL2  0.069314718055994530942f  // lambda*ln(2)

// softmin(a,b) = min - L*ln2*log2(1 + exp2(-|a-b|/(L*ln2)))
__device__ __forceinline__ float softmin2(float a, float b) {
    float mn = fminf(a, b);
    float t  = __builtin_amdgcn_exp2f(-K2 * fabsf(a - b));
    return mn - LL2 * __builtin_amdgcn_logf(1.0f + t);   // logf = v_log_f32 = log2
}

__device__ __forceinline__ float softmin3(float a, float b, float c) {
    float mn = fminf(fminf(a, b), c);   // v_min3_f32
    float s = __builtin_amdgcn_exp2f(-K2 * (a - mn))
            + __builtin_amdgcn_exp2f(-K2 * (b - mn))
            + __builtin_amdgcn_exp2f(-K2 * (c - mn));
    return mn - LL2 * __builtin_amdgcn_logf(s);
}

// DP1 (row-major over D): one row step, in-place with diagonal carry.
__device__ __forceinline__ void dp_row(float* R, const float* dr) {
    float diag = R[0];              // cum1[r-1, 0] = 0
    float oldR = R[1];
    R[1] = dr[0] + softmin3(diag, R[0], oldR);   // m = 1 boundary
    diag = oldR;
#pragma unroll
    for (int m = 2; m <= 16; ++m) {
        float o = R[m];
        R[m] = dr[m - 1] + softmin2(diag, R[m - 1]);
        diag = o;
    }
    R[17] = softmin3(diag, R[16], R[17]);        // m = 17 pad, d = 0, boundary
}

// DP2 (the DP on D^T, advanced column-major): one interior column step.
__device__ __forceinline__ void dp_col(float* C, const float* dr) {
    float diag2 = C[0];             // cum2[0, m-1]
    C[0] = C[0] + dr[0];            // row 0 of DP2 is a plain cumsum
#pragma unroll
    for (int l = 1; l < 16; ++l) {
        float o = C[l];
        C[l] = dr[l] + softmin2(diag2, o);
        diag2 = o;
    }
}

__global__ __launch_bounds__(256, 2)
void otam_fused_kernel(const float* __restrict__ sim, float* __restrict__ out) {
    const int t  = threadIdx.x & 63;
    const int wv = threadIdx.x >> 6;
    const int pair0 = blockIdx.x * 256 + wv * 64;

    __shared__ float lds_all[4 * 2048];              // 32 KB: 4 waves x 8 KB
    float* lds = lds_all + (wv << 11);               // wave-private -> no barriers

    const int u = t >> 3;                            // 0..7
    const int c = t & 7;                             // 0..7

    // global: instr i of chunk cc -> pair (pair0 + i*8 + u), bytes cc*128 + c*16
    const float* gbase = sim + (((size_t)(pair0 + u)) << 8) + (c << 2);
    // LDS write base (floats): slot (u*8 + (c^u)) ; + i*256 floats per instr
    float* wbase = lds + ((u * 8 + (c ^ u)) << 2);

    float R[18], C[16], dr[16];
    f32x4 ld[8];

#define LOADN(cc)                                                                  \
    _Pragma("unroll")                                                              \
    for (int i = 0; i < 8; ++i)                                                    \
        ld[i] = __builtin_nontemporal_load(                                        \
            reinterpret_cast<const f32x4*>(gbase + i * 2048 + (cc) * 32));

#define WRITEC()                                                                   \
    _Pragma("unroll")                                                              \
    for (int i = 0; i < 8; ++i) {                                                  \
        f32x4 w = 1.0f - ld[i];                                                    \
        *reinterpret_cast<f32x4*>(wbase + i * 256) = w;                            \
    }

#define READR(rr)                                                                  \
    _Pragma("unroll")                                                              \
    for (int k = 0; k < 4; ++k) {                                                  \
        f32x4 v = *reinterpret_cast<const f32x4*>(                                 \
            lds + t * 32 + ((((rr) * 4 + k) ^ c) << 2));                           \
        dr[k * 4 + 0] = v.x; dr[k * 4 + 1] = v.y;                                  \
        dr[k * 4 + 2] = v.z; dr[k * 4 + 3] = v.w;                                  \
    }

    // ---------- chunk 0 (rows 0,1) ----------
    LOADN(0);
    WRITEC();

    // row 0: DP1 row 0 = cumsum; DP2 column m=1 (boundary)
    READR(0);
    R[0] = 0.0f;
#pragma unroll
    for (int m = 1; m <= 16; ++m) R[m] = R[m - 1] + dr[m - 1];
    R[17] = R[16];
    C[0] = dr[0];
#pragma unroll
    for (int l = 1; l < 16; ++l)
        C[l] = dr[l] + softmin3(0.0f, 0.0f, C[l - 1]);

    LOADN(1);            // chunk 1 in flight during row 1 compute

    // row 1
    READR(1);
    dp_row(R, dr);
    dp_col(C, dr);

    // ---------- chunks 1..7 (rows 2..15), rolled loop ----------
    for (int cc = 1; cc < 8; ++cc) {
        WRITEC();        // waits this chunk's loads (issued one row-compute ago)
        READR(0);
        dp_row(R, dr);
        dp_col(C, dr);
        if (cc < 7) LOADN(cc + 1);   // next chunk flies during second row
        READR(1);
        dp_row(R, dr);
        dp_col(C, dr);
    }

    // ---------- DP2 final column m = 17 (d = 0, boundary) ----------
    {
        float diag2 = C[0];
#pragma unroll
        for (int l = 1; l < 16; ++l) {
            float o = C[l];
            C[l] = softmin3(diag2, o, C[l - 1]);
            diag2 = o;
        }
    }

    out[pair0 + t] = -0.5f * (R[17] + C[15]);
#undef LOADN
#undef WRITEC
#undef READR
}

extern "C" void kernel_launch(void* const* d_in, const int* in_sizes, int n_in,
                              void* d_out, int out_size, void* d_ws, size_t ws_size,
                              hipStream_t stream) {
    const float* sim = (const float*)d_in[0];
    float* out = (float*)d_out;
    int npairs = in_sizes[0] >> 8;          // 262144
    int grid = npairs >> 8;                 // 256 pairs per block
    otam_fused_kernel<<<grid, 256, 0, stream>>>(sim, out);
}

// Round 11
// 53.707 us; speedup vs baseline: 1.3281x; 1.0434x over previous
//
#include <hip/hip_runtime.h>

// OTAM cumulative-distance matching, fused forward+transposed DP, one pass.
// similarity: [2048, 128, 16, 16] f32 ; out: [2048, 128] f32
//
// v11 == v7 (best measured: 53.0 us, 5.06 TB/s effective, ~86-89% of copy
// ceiling steady-state). Reverts v10's nontemporal hint (-6%: discards the
// half-line L2 locality between consecutive chunks). Structure:
//   - fused DP1 (row-major) + DP2 (transposed DP, column-major) in one
//     streaming read of the 16x16 tile; 1 thread per (q,s) pair
//   - coalesced staging: 8 full 128B lines per global instr -> XOR-swizzled
//     LDS (b128 write+read, bank-conflict-free) -> per-thread row regs
//   - wave-private LDS quadrant: zero barriers
//   - mid-chunk prefetch: next chunk's loads issued between the two row
//     computes of the current chunk (compiler-tracked vmcnt, race-free)
//   - rolled main loop (full unroll blows 32KB L1I: R6, -22%)
//   - launch_bounds(256,2): (256,4) forces 64-VGPR alloc -> 870MB of scratch
//     spill traffic (R3, -5x)

#define K2   14.4269504088896340736f   // 1/(lambda*ln2), lambda = 0.1
#define LL2  0.069314718055994530942f  // lambda*ln(2)

// softmin(a,b) = min - L*ln2*log2(1 + exp2(-|a-b|/(L*ln2)))
__device__ __forceinline__ float softmin2(float a, float b) {
    float mn = fminf(a, b);
    float t  = __builtin_amdgcn_exp2f(-K2 * fabsf(a - b));
    return mn - LL2 * __builtin_amdgcn_logf(1.0f + t);   // logf = v_log_f32 = log2
}

__device__ __forceinline__ float softmin3(float a, float b, float c) {
    float mn = fminf(fminf(a, b), c);   // v_min3_f32
    float s = __builtin_amdgcn_exp2f(-K2 * (a - mn))
            + __builtin_amdgcn_exp2f(-K2 * (b - mn))
            + __builtin_amdgcn_exp2f(-K2 * (c - mn));
    return mn - LL2 * __builtin_amdgcn_logf(s);
}

// DP1 (row-major over D): one row step, in-place with diagonal carry.
__device__ __forceinline__ void dp_row(float* R, const float* dr) {
    float diag = R[0];              // cum1[r-1, 0] = 0
    float oldR = R[1];
    R[1] = dr[0] + softmin3(diag, R[0], oldR);   // m = 1 boundary
    diag = oldR;
#pragma unroll
    for (int m = 2; m <= 16; ++m) {
        float o = R[m];
        R[m] = dr[m - 1] + softmin2(diag, R[m - 1]);
        diag = o;
    }
    R[17] = softmin3(diag, R[16], R[17]);        // m = 17 pad, d = 0, boundary
}

// DP2 (the DP on D^T, advanced column-major): one interior column step.
__device__ __forceinline__ void dp_col(float* C, const float* dr) {
    float diag2 = C[0];             // cum2[0, m-1]
    C[0] = C[0] + dr[0];            // row 0 of DP2 is a plain cumsum
#pragma unroll
    for (int l = 1; l < 16; ++l) {
        float o = C[l];
        C[l] = dr[l] + softmin2(diag2, o);
        diag2 = o;
    }
}

__global__ __launch_bounds__(256, 2)
void otam_fused_kernel(const float* __restrict__ sim, float* __restrict__ out) {
    const int t  = threadIdx.x & 63;
    const int wv = threadIdx.x >> 6;
    const int pair0 = blockIdx.x * 256 + wv * 64;

    __shared__ float lds_all[4 * 2048];              // 32 KB: 4 waves x 8 KB
    float* lds = lds_all + (wv << 11);               // wave-private -> no barriers

    const int u = t >> 3;                            // 0..7
    const int c = t & 7;                             // 0..7

    // global: instr i of chunk cc -> pair (pair0 + i*8 + u), bytes cc*128 + c*16
    const float* gbase = sim + (((size_t)(pair0 + u)) << 8) + (c << 2);
    // LDS write base (floats): slot (u*8 + (c^u)) ; + i*256 floats per instr
    float* wbase = lds + ((u * 8 + (c ^ u)) << 2);

    float R[18], C[16], dr[16];
    float4 ld[8];

#define LOADN(cc)                                                                  \
    _Pragma("unroll")                                                              \
    for (int i = 0; i < 8; ++i)                                                    \
        ld[i] = *reinterpret_cast<const float4*>(gbase + i * 2048 + (cc) * 32);

#define WRITEC()                                                                   \
    _Pragma("unroll")                                                              \
    for (int i = 0; i < 8; ++i) {                                                  \
        float4 w;                                                                  \
        w.x = 1.0f - ld[i].x; w.y = 1.0f - ld[i].y;                                \
        w.z = 1.0f - ld[i].z; w.w = 1.0f - ld[i].w;                                \
        *reinterpret_cast<float4*>(wbase + i * 256) = w;                           \
    }

#define READR(rr)                                                                  \
    _Pragma("unroll")                                                              \
    for (int k = 0; k < 4; ++k) {                                                  \
        float4 v = *reinterpret_cast<const float4*>(                               \
            lds + t * 32 + ((((rr) * 4 + k) ^ c) << 2));                           \
        dr[k * 4 + 0] = v.x; dr[k * 4 + 1] = v.y;                                  \
        dr[k * 4 + 2] = v.z; dr[k * 4 + 3] = v.w;                                  \
    }

    // ---------- chunk 0 (rows 0,1) ----------
    LOADN(0);
    WRITEC();

    // row 0: DP1 row 0 = cumsum; DP2 column m=1 (boundary)
    READR(0);
    R[0] = 0.0f;
#pragma unroll
    for (int m = 1; m <= 16; ++m) R[m] = R[m - 1] + dr[m - 1];
    R[17] = R[16];
    C[0] = dr[0];
#pragma unroll
    for (int l = 1; l < 16; ++l)
        C[l] = dr[l] + softmin3(0.0f, 0.0f, C[l - 1]);

    LOADN(1);            // chunk 1 in flight during row 1 compute

    // row 1
    READR(1);
    dp_row(R, dr);
    dp_col(C, dr);

    // ---------- chunks 1..7 (rows 2..15), rolled loop ----------
    for (int cc = 1; cc < 8; ++cc) {
        WRITEC();        // waits this chunk's loads (issued one row-compute ago)
        READR(0);
        dp_row(R, dr);
        dp_col(C, dr);
        if (cc < 7) LOADN(cc + 1);   // next chunk flies during second row
        READR(1);
        dp_row(R, dr);
        dp_col(C, dr);
    }

    // ---------- DP2 final column m = 17 (d = 0, boundary) ----------
    {
        float diag2 = C[0];
#pragma unroll
        for (int l = 1; l < 16; ++l) {
            float o = C[l];
            C[l] = softmin3(diag2, o, C[l - 1]);
            diag2 = o;
        }
    }

    out[pair0 + t] = -0.5f * (R[17] + C[15]);
#undef LOADN
#undef WRITEC
#undef READR
}

extern "C" void kernel_launch(void* const* d_in, const int* in_sizes, int n_in,
                              void* d_out, int out_size, void* d_ws, size_t ws_size,
                              hipStream_t stream) {
    const float* sim = (const float*)d_in[0];
    float* out = (float*)d_out;
    int npairs = in_sizes[0] >> 8;          // 262144
    int grid = npairs >> 8;                 // 256 pairs per block
    otam_fused_kernel<<<grid, 256, 0, stream>>>(sim, out);
}